// Round 1
// baseline (57616.235 us; speedup 1.0000x reference)
//
#include <hip/hip_runtime.h>
#include <hip/hip_cooperative_groups.h>
#include <math.h>

namespace cg = cooperative_groups;

#define B_ 64
#define T_ 700
#define U_ 400

// ws layout: hbuf[3 layers][2 parity][U_][B_] fp32  (614400 B) + 768 B prefetch slack
#define HBUF_BYTES (3 * 2 * U_ * B_ * sizeof(float))

__device__ __forceinline__ float sig_(float v) { return 1.f / (1.f + __expf(-v)); }

// Pipelined persistent LSTM:
//  superstep s: L0 computes t=s, L1 t=s-1, L2 t=s-2, OUT t=s-3. One grid.sync per superstep.
//  blocks 0..49   : layer 0, 8 units each (32 gate-cols), K=400 (Wh only; x*Wx0 added in gate phase)
//  blocks 50..149 : layer 1, 4 units each (16 gate-cols), K=800 ([Wx1;Wh1])
//  blocks 150..249: layer 2, 4 units each (16 gate-cols), K=800 ([Wx2;Wh2])
//  block 250      : output projection h2 @ Wd + bd
__global__ void __launch_bounds__(256, 1)
lstm_pipe(const float* __restrict__ x,
          const float* __restrict__ Wx0,
          const float* __restrict__ Wx1,
          const float* __restrict__ Wx2,
          const float* __restrict__ Wh,
          const float* __restrict__ bias,
          const float* __restrict__ pi,
          const float* __restrict__ pf,
          const float* __restrict__ po,
          const float* __restrict__ Wd,
          const float* __restrict__ bd,
          float* __restrict__ out,
          float* __restrict__ hbuf)
{
    __shared__ alignas(16) float wlds[12800];   // 51.2 KB: [c][K] transposed weight slice
    __shared__ alignas(16) float rbuf[3264];    // 13.0 KB: cross-wave partial-z reduce

    const int blk  = blockIdx.x;
    const int tid  = threadIdx.x;
    const int lane = tid & 63;
    const int wv   = tid >> 6;

    int layer, u0;
    if      (blk < 50)  { layer = 0; u0 = blk * 8; }
    else if (blk < 150) { layer = 1; u0 = (blk - 50) * 4; }
    else if (blk < 250) { layer = 2; u0 = (blk - 150) * 4; }
    else                { layer = 3; u0 = 0; }

    // ---- one-time: stage this WG's weight slice into LDS, transposed to [c][k] ----
    if (layer == 0) {
        // c = g*8 + ul  ->  global col = g*400 + u0 + ul ; rows = Wh[0][k][col], K=400
        for (int i = tid; i < 32 * 400; i += 256) {
            const int c = i & 31, k = i >> 5;
            const int col = ((c >> 3) * U_) + u0 + (c & 7);
            wlds[c * 400 + k] = Wh[(size_t)k * 1600 + col];
        }
    } else if (layer < 3) {
        // c = g*4 + ul ; rows 0..399 = Wx_l[k][col], rows 400..799 = Wh[l][k-400][col]
        const float* __restrict__ Wxl = (layer == 1) ? Wx1 : Wx2;
        for (int i = tid; i < 16 * 800; i += 256) {
            const int c = i & 15, k = i >> 4;
            const int col = ((c >> 2) * U_) + u0 + (c & 3);
            wlds[c * 800 + k] = (k < 400)
                ? Wxl[(size_t)k * 1600 + col]
                : Wh[((size_t)layer * U_ + (k - 400)) * 1600 + col];
        }
    }
    __syncthreads();

    float cst[8];                      // persistent cell state (wave-0 lanes only)
#pragma unroll
    for (int i = 0; i < 8; ++i) cst[i] = 0.f;

    cg::grid_group grid = cg::this_grid();

    for (int s = 0; s < T_ + 3; ++s) {
        const int pr = (s + 1) & 1;    // parity written last superstep (read side)
        const int pw = s & 1;          // parity we write this superstep

        if (layer == 0) {
            const int t = s;
            if (t < T_) {
                float acc[32];
#pragma unroll
                for (int c = 0; c < 32; ++c) acc[c] = 0.f;
                // wave wv handles k in [wv*100, wv*100+100) of h0[t-1]
                const float* __restrict__ hp =
                    hbuf + ((size_t)pr * U_ + wv * 100) * B_ + lane;
                const int wr = wv * 100;
                float a0 = hp[0], a1 = hp[64], a2 = hp[128], a3 = hp[192];
                for (int kk = 0; kk < 100; kk += 4) {
                    const float n0 = hp[(kk + 4) * 64];
                    const float n1 = hp[(kk + 5) * 64];
                    const float n2 = hp[(kk + 6) * 64];
                    const float n3 = hp[(kk + 7) * 64];
#pragma unroll
                    for (int c = 0; c < 32; ++c) {
                        const float4 w = *(const float4*)(wlds + c * 400 + wr + kk);
                        acc[c] += a0 * w.x + a1 * w.y + a2 * w.z + a3 * w.w;
                    }
                    a0 = n0; a1 = n1; a2 = n2; a3 = n3;
                }
                // sequential pairwise reduce into wave 0 (rbuf too small for 3 slots of 32)
                for (int r = 1; r <= 3; ++r) {
                    if (wv == r) {
#pragma unroll
                        for (int c = 0; c < 32; ++c) rbuf[lane * 33 + c] = acc[c];
                    }
                    __syncthreads();
                    if (wv == 0) {
#pragma unroll
                        for (int c = 0; c < 32; ++c) acc[c] += rbuf[lane * 33 + c];
                    }
                    __syncthreads();
                }
                if (wv == 0) {
                    const int b = lane;
                    const float x0 = x[((size_t)b * T_ + t) * 3 + 0];
                    const float x1 = x[((size_t)b * T_ + t) * 3 + 1];
                    const float x2 = x[((size_t)b * T_ + t) * 3 + 2];
                    float* __restrict__ hw = hbuf + (size_t)pw * U_ * B_;
#pragma unroll
                    for (int ul = 0; ul < 8; ++ul) {
                        const int ug = u0 + ul;
                        float zz[4];
#pragma unroll
                        for (int g = 0; g < 4; ++g) {
                            const int col = g * U_ + ug;
                            zz[g] = acc[g * 8 + ul] + bias[col]
                                  + x0 * Wx0[col] + x1 * Wx0[1600 + col] + x2 * Wx0[3200 + col];
                        }
                        const float cp = cst[ul];
                        const float ig = sig_(zz[0] + pi[ug] * cp);
                        const float fg = sig_(zz[1] + pf[ug] * cp);
                        const float cn = fg * cp + ig * tanhf(zz[2]);
                        const float og = sig_(zz[3] + po[ug] * cn);
                        cst[ul] = cn;
                        hw[(size_t)ug * B_ + b] = og * tanhf(cn);
                    }
                }
            }
        } else if (layer < 3) {
            const int t = s - layer;
            if (t >= 0 && t < T_) {
                float acc[16];
#pragma unroll
                for (int c = 0; c < 16; ++c) acc[c] = 0.f;
                // waves 0,1: k in [0,400) -> h_{l-1}[t]; waves 2,3: k in [400,800) -> h_l[t-1]
                const int src  = (wv < 2) ? (layer - 1) : layer;
                const int hrow = (wv & 1) * 200;
                const int wr   = wv * 200;
                const float* __restrict__ hp =
                    hbuf + ((size_t)(src * 2 + pr) * U_ + hrow) * B_ + lane;
                float a0 = hp[0], a1 = hp[64], a2 = hp[128], a3 = hp[192];
                for (int kk = 0; kk < 200; kk += 4) {
                    const float n0 = hp[(kk + 4) * 64];
                    const float n1 = hp[(kk + 5) * 64];
                    const float n2 = hp[(kk + 6) * 64];
                    const float n3 = hp[(kk + 7) * 64];
#pragma unroll
                    for (int c = 0; c < 16; ++c) {
                        const float4 w = *(const float4*)(wlds + c * 800 + wr + kk);
                        acc[c] += a0 * w.x + a1 * w.y + a2 * w.z + a3 * w.w;
                    }
                    a0 = n0; a1 = n1; a2 = n2; a3 = n3;
                }
                // single-round parallel reduce into wave 0
                if (wv >= 1) {
#pragma unroll
                    for (int c = 0; c < 16; ++c)
                        rbuf[((wv - 1) * 64 + lane) * 17 + c] = acc[c];
                }
                __syncthreads();
                if (wv == 0) {
                    const int b = lane;
#pragma unroll
                    for (int c = 0; c < 16; ++c)
                        acc[c] += rbuf[(0 * 64 + b) * 17 + c]
                                + rbuf[(1 * 64 + b) * 17 + c]
                                + rbuf[(2 * 64 + b) * 17 + c];
                    float* __restrict__ hw = hbuf + (size_t)(layer * 2 + pw) * U_ * B_;
#pragma unroll
                    for (int ul = 0; ul < 4; ++ul) {
                        const int ug = u0 + ul;
                        const float zi = acc[0 * 4 + ul] + bias[layer * 1600 + 0 * U_ + ug];
                        const float zf = acc[1 * 4 + ul] + bias[layer * 1600 + 1 * U_ + ug];
                        const float zg = acc[2 * 4 + ul] + bias[layer * 1600 + 2 * U_ + ug];
                        const float zo = acc[3 * 4 + ul] + bias[layer * 1600 + 3 * U_ + ug];
                        const float cp = cst[ul];
                        const float ig = sig_(zi + pi[layer * U_ + ug] * cp);
                        const float fg = sig_(zf + pf[layer * U_ + ug] * cp);
                        const float cn = fg * cp + ig * tanhf(zg);
                        const float og = sig_(zo + po[layer * U_ + ug] * cn);
                        cst[ul] = cn;
                        hw[(size_t)ug * B_ + b] = og * tanhf(cn);
                    }
                }
            }
        } else {
            // output projection: out[b][t][f] = h2[t][:,b] . Wd[:,f] + bd[f]
            const int t = s - 3;
            if (t >= 0) {
                float f0 = 0.f, f1 = 0.f, f2 = 0.f;
                const float* __restrict__ hp =
                    hbuf + ((size_t)(4 + pr) * U_ + wv * 100) * B_ + lane;
                for (int u = 0; u < 100; ++u) {
                    const float hv = hp[u * 64];
                    const int  ug = wv * 100 + u;
                    f0 += hv * Wd[ug * 3 + 0];
                    f1 += hv * Wd[ug * 3 + 1];
                    f2 += hv * Wd[ug * 3 + 2];
                }
                if (wv >= 1) {
                    rbuf[((wv - 1) * 64 + lane) * 4 + 0] = f0;
                    rbuf[((wv - 1) * 64 + lane) * 4 + 1] = f1;
                    rbuf[((wv - 1) * 64 + lane) * 4 + 2] = f2;
                }
                __syncthreads();
                if (wv == 0) {
#pragma unroll
                    for (int sl = 0; sl < 3; ++sl) {
                        f0 += rbuf[(sl * 64 + lane) * 4 + 0];
                        f1 += rbuf[(sl * 64 + lane) * 4 + 1];
                        f2 += rbuf[(sl * 64 + lane) * 4 + 2];
                    }
                    out[((size_t)lane * T_ + t) * 3 + 0] = f0 + bd[0];
                    out[((size_t)lane * T_ + t) * 3 + 1] = f1 + bd[1];
                    out[((size_t)lane * T_ + t) * 3 + 2] = f2 + bd[2];
                }
            }
        }

        __threadfence();   // release h writes to device scope
        grid.sync();
        __threadfence();   // acquire: invalidate L1 so re-used parity buffers aren't stale
    }
}

extern "C" void kernel_launch(void* const* d_in, const int* in_sizes, int n_in,
                              void* d_out, int out_size, void* d_ws, size_t ws_size,
                              hipStream_t stream) {
    const float* x    = (const float*)d_in[0];
    const float* Wx0  = (const float*)d_in[1];
    const float* Wx1  = (const float*)d_in[2];
    const float* Wx2  = (const float*)d_in[3];
    const float* Wh   = (const float*)d_in[4];
    const float* bias = (const float*)d_in[5];
    const float* pi   = (const float*)d_in[6];
    const float* pf   = (const float*)d_in[7];
    const float* po   = (const float*)d_in[8];
    const float* Wd   = (const float*)d_in[9];
    const float* bd   = (const float*)d_in[10];
    float* out  = (float*)d_out;
    float* hbuf = (float*)d_ws;

    // h history buffers must start at zero every launch (ws is re-poisoned to 0xAA)
    hipMemsetAsync(d_ws, 0, HBUF_BYTES, stream);

    void* args[] = { (void*)&x, (void*)&Wx0, (void*)&Wx1, (void*)&Wx2, (void*)&Wh,
                     (void*)&bias, (void*)&pi, (void*)&pf, (void*)&po,
                     (void*)&Wd, (void*)&bd, (void*)&out, (void*)&hbuf };

    hipError_t err = hipLaunchCooperativeKernel((void*)lstm_pipe, dim3(251), dim3(256),
                                                args, 0, stream);
    if (err != hipSuccess) {
        // fallback: 251 blocks x 256 thr @ ~64KB LDS is 1 WG/CU -> co-resident anyway
        hipLaunchKernelGGL(lstm_pipe, dim3(251), dim3(256), 0, stream,
                           x, Wx0, Wx1, Wx2, Wh, bias, pi, pf, po, Wd, bd, out, hbuf);
    }
}

// Round 2
// 21679.836 us; speedup vs baseline: 2.6576x; 2.6576x over previous
//
#include <hip/hip_runtime.h>
#include <math.h>

#define B_ 64
#define T_ 700
#define U_ 400
#define NF 704                     // flag slots per array (>= T_)

#define HBUF_FLOATS (3 * 2 * U_ * B_)          // [layer][parity][u][b]
#define HBUF_BYTES  (HBUF_FLOATS * 4)
#define FLAG_BYTES  (4 * NF * 4)

// ---- agent-scope (cross-XCD coherent) helpers: no fences, no L2 invalidation ----
__device__ __forceinline__ float agload(const float* p) {
    return __hip_atomic_load(p, __ATOMIC_RELAXED, __HIP_MEMORY_SCOPE_AGENT);
}
__device__ __forceinline__ void agstore(float* p, float v) {
    __hip_atomic_store(p, v, __ATOMIC_RELAXED, __HIP_MEMORY_SCOPE_AGENT);
}
__device__ __forceinline__ unsigned agloadu(const unsigned* p) {
    return __hip_atomic_load(p, __ATOMIC_RELAXED, __HIP_MEMORY_SCOPE_AGENT);
}

__device__ __forceinline__ float sig_(float v) {
    return __builtin_amdgcn_rcpf(1.f + __expf(-v));
}
__device__ __forceinline__ float tanh_(float v) {
    return 1.f - 2.f * __builtin_amdgcn_rcpf(__expf(2.f * v) + 1.f);
}

__device__ __forceinline__ void waitflag(const unsigned* f, unsigned target) {
    while (agloadu(f) < target) __builtin_amdgcn_s_sleep(1);
}

// 25-group software-pipelined GEMM slice: 5 slots x G elements prefetch (sc1 loads),
// acc[C] += h[k] * wlds[c][wr+k] over this wave's K range of 25*G.
// hp: h base + lane (element stride 64 floats). wl: LDS weights, row stride KROW.
template<int C, int G>
__device__ __forceinline__ void gemm25(const float* __restrict__ hp,
                                       const float* __restrict__ wl,
                                       const int KROW, const int wr,
                                       float* __restrict__ acc)
{
    float pre[5][G];
#pragma unroll
    for (int g = 0; g < 5; ++g)
#pragma unroll
        for (int j = 0; j < G; ++j)
            pre[g][j] = agload(hp + (size_t)(g * G + j) * B_);

#pragma unroll
    for (int o = 0; o < 5; ++o) {
#pragma unroll
        for (int g = 0; g < 5; ++g) {
            const int kk = (o * 5 + g) * G;
            float cur[G];
#pragma unroll
            for (int j = 0; j < G; ++j) cur[j] = pre[g][j];
            if (o < 4) {   // refill this slot for the next outer round (stays 5 groups ahead)
#pragma unroll
                for (int j = 0; j < G; ++j)
                    pre[g][j] = agload(hp + (size_t)(kk + 5 * G + j) * B_);
            }
#pragma unroll
            for (int c = 0; c < C; ++c) {
                const float* wrow = wl + c * KROW + wr + kk;
#pragma unroll
                for (int j4 = 0; j4 < G / 4; ++j4) {
                    const float4 w = *(const float4*)(wrow + j4 * 4);
                    acc[c] += cur[j4 * 4 + 0] * w.x + cur[j4 * 4 + 1] * w.y
                            + cur[j4 * 4 + 2] * w.z + cur[j4 * 4 + 3] * w.w;
                }
            }
        }
    }
}

//  blocks 0..49   : layer 0, 8 units (32 cols), K=400 (Wh0; x*Wx0 added in gate phase)
//  blocks 50..149 : layer 1, 4 units (16 cols), K=800 ([Wx1;Wh1])
//  blocks 150..249: layer 2, 4 units (16 cols), K=800 ([Wx2;Wh2])
//  block 250      : output projection h2 @ Wd + bd
//  Sync: per-(layer,t) monotonic counters; no grid barrier, no fences.
__global__ void __launch_bounds__(256, 1)
lstm_flags(const float* __restrict__ x,
           const float* __restrict__ Wx0,
           const float* __restrict__ Wx1,
           const float* __restrict__ Wx2,
           const float* __restrict__ Wh,
           const float* __restrict__ bias,
           const float* __restrict__ pi,
           const float* __restrict__ pf,
           const float* __restrict__ po,
           const float* __restrict__ Wd,
           const float* __restrict__ bd,
           float* __restrict__ out,
           float* __restrict__ ws)
{
    __shared__ alignas(16) float wlds[12800];        // 51.2 KB [c][K]
    __shared__ alignas(16) float rbuf[4 * 64 * 33];  // 33.8 KB cross-wave reduce

    float* hbuf = ws;
    unsigned* F0 = (unsigned*)(ws + HBUF_FLOATS);
    unsigned* F1 = F0 + NF;
    unsigned* F2 = F1 + NF;
    unsigned* FO = F2 + NF;

    const int blk  = blockIdx.x;
    const int tid  = threadIdx.x;
    const int lane = tid & 63;
    const int wv   = tid >> 6;

    int layer, u0;
    if      (blk < 50)  { layer = 0; u0 = blk * 8; }
    else if (blk < 150) { layer = 1; u0 = (blk - 50) * 4; }
    else if (blk < 250) { layer = 2; u0 = (blk - 150) * 4; }
    else                { layer = 3; u0 = 0; }

    // ---- one-time weight staging into LDS, transposed to [c][k] ----
    if (layer == 0) {
        for (int i = tid; i < 32 * 400; i += 256) {
            const int c = i & 31, k = i >> 5;
            const int col = ((c >> 3) * U_) + u0 + (c & 7);
            wlds[c * 400 + k] = Wh[(size_t)k * 1600 + col];
        }
    } else if (layer < 3) {
        const float* __restrict__ Wxl = (layer == 1) ? Wx1 : Wx2;
        for (int i = tid; i < 16 * 800; i += 256) {
            const int c = i & 15, k = i >> 4;
            const int col = ((c >> 2) * U_) + u0 + (c & 3);
            wlds[c * 800 + k] = (k < 400)
                ? Wxl[(size_t)k * 1600 + col]
                : Wh[((size_t)layer * U_ + (k - 400)) * 1600 + col];
        }
    } else {
        for (int i = tid; i < 3 * 400; i += 256) {
            const int c = i / 400, k = i - c * 400;
            wlds[c * 400 + k] = Wd[k * 3 + c];
        }
    }
    __syncthreads();

    float cst[2] = {0.f, 0.f};   // per-wave persistent cell state (L0: 2 units/wave)

    for (int t = 0; t < T_; ++t) {
        // ---- wait for inputs + overwrite-safety (monotonic counters) ----
        if (tid == 0) {
            if (layer == 0) {
                if (t >= 1) waitflag(F0 + t - 1, 50);
                if (t >= 2) waitflag(F1 + t - 2, 100);
            } else if (layer == 1) {
                waitflag(F0 + t, 50);
                if (t >= 1) waitflag(F1 + t - 1, 100);
                if (t >= 2) waitflag(F2 + t - 2, 100);
            } else if (layer == 2) {
                waitflag(F1 + t, 100);
                if (t >= 1) waitflag(F2 + t - 1, 100);
                if (t >= 2) waitflag(FO + t - 2, 1);
            } else {
                waitflag(F2 + t, 100);
            }
        }
        __syncthreads();

        const int pw = t & 1, pr = (t + 1) & 1;

        if (layer == 0) {
            float acc[32];
#pragma unroll
            for (int c = 0; c < 32; ++c) acc[c] = 0.f;
            const float* hread = hbuf + (size_t)(0 * 2 + pr) * U_ * B_;
            gemm25<32, 4>(hread + (size_t)(wv * 100) * B_ + lane, wlds, 400, wv * 100, acc);
#pragma unroll
            for (int c = 0; c < 32; ++c) rbuf[(wv * 64 + lane) * 33 + c] = acc[c];
            __syncthreads();

            const float x0 = x[((size_t)lane * T_ + t) * 3 + 0];
            const float x1 = x[((size_t)lane * T_ + t) * 3 + 1];
            const float x2 = x[((size_t)lane * T_ + t) * 3 + 2];
            float* hw = hbuf + (size_t)(0 * 2 + pw) * U_ * B_;
#pragma unroll
            for (int q = 0; q < 2; ++q) {
                const int ul = wv + q * 4;
                const int ug = u0 + ul;
                float z[4];
#pragma unroll
                for (int g = 0; g < 4; ++g) {
                    float s = 0.f;
#pragma unroll
                    for (int w2 = 0; w2 < 4; ++w2) s += rbuf[(w2 * 64 + lane) * 33 + g * 8 + ul];
                    const int col = g * U_ + ug;
                    z[g] = s + bias[col] + x0 * Wx0[col] + x1 * Wx0[1600 + col] + x2 * Wx0[3200 + col];
                }
                const float cp = cst[q];
                const float ig = sig_(z[0] + pi[ug] * cp);
                const float fg = sig_(z[1] + pf[ug] * cp);
                const float cn = fg * cp + ig * tanh_(z[2]);
                const float og = sig_(z[3] + po[ug] * cn);
                cst[q] = cn;
                agstore(hw + (size_t)ug * B_ + lane, og * tanh_(cn));
            }
        } else if (layer < 3) {
            float acc[16];
#pragma unroll
            for (int c = 0; c < 16; ++c) acc[c] = 0.f;
            // waves 0,1: h_{l-1}[t] (parity pw); waves 2,3: h_l[t-1] (parity pr)
            const int srcbuf = (wv < 2) ? ((layer - 1) * 2 + pw) : (layer * 2 + pr);
            const float* hread = hbuf + (size_t)srcbuf * U_ * B_ + (size_t)((wv & 1) * 200) * B_ + lane;
            gemm25<16, 8>(hread, wlds, 800, wv * 200, acc);
#pragma unroll
            for (int c = 0; c < 16; ++c) rbuf[(wv * 64 + lane) * 33 + c] = acc[c];
            __syncthreads();

            const int ug = u0 + wv;            // one unit per wave
            float z[4];
#pragma unroll
            for (int g = 0; g < 4; ++g) {
                float s = 0.f;
#pragma unroll
                for (int w2 = 0; w2 < 4; ++w2) s += rbuf[(w2 * 64 + lane) * 33 + g * 4 + wv];
                z[g] = s + bias[layer * 1600 + g * U_ + ug];
            }
            const float cp = cst[0];
            const float ig = sig_(z[0] + pi[layer * U_ + ug] * cp);
            const float fg = sig_(z[1] + pf[layer * U_ + ug] * cp);
            const float cn = fg * cp + ig * tanh_(z[2]);
            const float og = sig_(z[3] + po[layer * U_ + ug] * cn);
            cst[0] = cn;
            agstore(hbuf + (size_t)(layer * 2 + pw) * U_ * B_ + (size_t)ug * B_ + lane, og * tanh_(cn));
        } else {
            float acc[3] = {0.f, 0.f, 0.f};
            const float* hread = hbuf + (size_t)(2 * 2 + pw) * U_ * B_ + (size_t)(wv * 100) * B_ + lane;
            gemm25<3, 4>(hread, wlds, 400, wv * 100, acc);
#pragma unroll
            for (int c = 0; c < 3; ++c) rbuf[(wv * 64 + lane) * 33 + c] = acc[c];
            __syncthreads();
            if (wv == 0) {
                float f0 = 0.f, f1 = 0.f, f2 = 0.f;
#pragma unroll
                for (int w2 = 0; w2 < 4; ++w2) {
                    f0 += rbuf[(w2 * 64 + lane) * 33 + 0];
                    f1 += rbuf[(w2 * 64 + lane) * 33 + 1];
                    f2 += rbuf[(w2 * 64 + lane) * 33 + 2];
                }
                out[((size_t)lane * T_ + t) * 3 + 0] = f0 + bd[0];
                out[((size_t)lane * T_ + t) * 3 + 1] = f1 + bd[1];
                out[((size_t)lane * T_ + t) * 3 + 2] = f2 + bd[2];
            }
        }

        // ---- publish: drain sc1 stores to coherence point, then bump counter ----
        asm volatile("s_waitcnt vmcnt(0)" ::: "memory");
        __syncthreads();
        if (tid == 0) {
            unsigned* f = (layer == 0) ? (F0 + t) : (layer == 1) ? (F1 + t)
                        : (layer == 2) ? (F2 + t) : (FO + t);
            __hip_atomic_fetch_add(f, 1u, __ATOMIC_RELAXED, __HIP_MEMORY_SCOPE_AGENT);
        }
    }
}

extern "C" void kernel_launch(void* const* d_in, const int* in_sizes, int n_in,
                              void* d_out, int out_size, void* d_ws, size_t ws_size,
                              hipStream_t stream) {
    const float* x    = (const float*)d_in[0];
    const float* Wx0  = (const float*)d_in[1];
    const float* Wx1  = (const float*)d_in[2];
    const float* Wx2  = (const float*)d_in[3];
    const float* Wh   = (const float*)d_in[4];
    const float* bias = (const float*)d_in[5];
    const float* pi   = (const float*)d_in[6];
    const float* pf   = (const float*)d_in[7];
    const float* po   = (const float*)d_in[8];
    const float* Wd   = (const float*)d_in[9];
    const float* bd   = (const float*)d_in[10];
    float* out = (float*)d_out;
    float* ws  = (float*)d_ws;

    // zero h double-buffers + flag counters (ws is poisoned before every launch)
    hipMemsetAsync(d_ws, 0, HBUF_BYTES + FLAG_BYTES, stream);

    void* args[] = { (void*)&x, (void*)&Wx0, (void*)&Wx1, (void*)&Wx2, (void*)&Wh,
                     (void*)&bias, (void*)&pi, (void*)&pf, (void*)&po,
                     (void*)&Wd, (void*)&bd, (void*)&out, (void*)&ws };

    hipError_t err = hipLaunchCooperativeKernel((void*)lstm_flags, dim3(251), dim3(256),
                                                args, 0, stream);
    if (err != hipSuccess) {
        // 251 WGs x 256 thr @ ~85KB LDS = 1 WG/CU on 256 CUs -> co-resident anyway
        hipLaunchKernelGGL(lstm_flags, dim3(251), dim3(256), 0, stream,
                           x, Wx0, Wx1, Wx2, Wh, bias, pi, pf, po, Wd, bd, out, ws);
    }
}